// Round 8
// baseline (277.354 us; speedup 1.0000x reference)
//
#include <hip/hip_runtime.h>

constexpr int NN  = 20000;   // nodes (= 625 * 32 exactly)
constexpr int NE  = 160000;  // edges (= 625 * 256)
constexpr int CAP = 32;      // bucket capacity (deg ~ Poisson(8); P(deg>32) ~ 0)
constexpr int TN  = 32;      // node tile per block
constexpr int NBM = 16;      // blocks in MLP kernel

// ---- agent-scope helpers (MLP inter-block traffic) ------------------------
__device__ inline void gstore(float* p, float v) {
    __hip_atomic_store(p, v, __ATOMIC_RELAXED, __HIP_MEMORY_SCOPE_AGENT);
}
__device__ inline float gload(const float* p) {
    return __hip_atomic_load(p, __ATOMIC_RELAXED, __HIP_MEMORY_SCOPE_AGENT);
}
__device__ inline void mbarrier(int* ctr, int target, bool wait) {
    __syncthreads();
    if (threadIdx.x == 0) {
        __threadfence();
        __hip_atomic_fetch_add(ctr, 1, __ATOMIC_ACQ_REL, __HIP_MEMORY_SCOPE_AGENT);
        if (wait)
            while (__hip_atomic_load(ctr, __ATOMIC_ACQUIRE, __HIP_MEMORY_SCOPE_AGENT) < target) {}
    }
    __syncthreads();
}

// ===========================================================================
// D2: build src-major edge buckets. For edge (src,tgt):
//   slot_s = src*CAP + q_s holds: adj_t[slot_s] = tgt*CAP + q_t (msg dest slot)
//                                 e_src[slot_s*8..] = e[eid*8..]
// ===========================================================================
__global__ __launch_bounds__(256)
void fill_kernel(const int* __restrict__ eidx, const float* __restrict__ e,
                 int* __restrict__ cnt_t, int* __restrict__ cnt_s,
                 int* __restrict__ adj_t, float* __restrict__ e_src)
{
    const int eid = blockIdx.x * 256 + threadIdx.x;     // NE == 625*256
    const int2 st = ((const int2*)eidx)[eid];
    const int qt = atomicAdd(&cnt_t[st.y], 1);
    const int qs = atomicAdd(&cnt_s[st.x], 1);
    if (qs < CAP) {
        const size_t ss = (size_t)st.x * CAP + qs;
        adj_t[ss] = (qt < CAP) ? st.y * CAP + qt : -1;
        const float4* e4 = (const float4*)(e + (size_t)eid * 8);
        float4* o4 = (float4*)(e_src + ss * 8);
        o4[0] = e4[0];
        o4[1] = e4[1];
    }
}

// ===========================================================================
// Fused layer kernel. Block owns nodes [n0, n0+TN).
//  A) h-tile: FIRST ? x rows : relu(root_prev + sum of own tgt-bucket msgs)
//  B) GEMM h-tile @ What (staged in 2 LDS halves) -> own P rows (global)
//     P[n, s*FO2+o]: s<8 = We channels, s==8 = be, s==9 = root2@h + b2
//  C) for own out-edges: msg = P[n,8ch] + sum_s e_s * P[n,s ch]  (block-local
//     P reads, L1/L2 hit) -> scatter into target's bucket slot.
// ===========================================================================
template<int FI, int FO2, bool FIRST>
__global__ __launch_bounds__(256)
void layer_kernel(const float* __restrict__ x,      // FIRST only
                  const float* __restrict__ Pprev,  // !FIRST: width 10*FI
                  const float* __restrict__ msgin,  // !FIRST: tgt buckets, width FI
                  const int* __restrict__ cnt_t, const int* __restrict__ cnt_s,
                  const int* __restrict__ adj_t, const float* __restrict__ e_src,
                  const float* __restrict__ We, const float* __restrict__ be,
                  const float* __restrict__ root, const float* __restrict__ bias,
                  float* __restrict__ Pout,         // width 10*FO2
                  float* __restrict__ msgout)       // tgt buckets, width FO2
{
    constexpr int PW  = 10 * FO2;
    constexpr int C4  = PW / 4;        // float4 cols of P row
    constexpr int C4H = C4 / 2;        // staged half
    constexpr int O4  = FO2 / 4;
    constexpr int PWP = 10 * FI;
    constexpr int HS  = FI + 4;        // htile stride (16B-aligned, alias-break)

    __shared__ float Wlds[FI * C4H * 4];
    __shared__ float htile[TN * HS];
    const int tid = threadIdx.x;
    const int n0 = blockIdx.x * TN;

    // ---- phase A ----
    if (FIRST) {
        for (int t = tid; t < TN * (FI / 4); t += 256) {
            const int nl = t / (FI / 4), fq = t % (FI / 4);
            ((float4*)&htile[nl * HS])[fq] =
                ((const float4*)(x + (size_t)(n0 + nl) * FI))[fq];
        }
    } else {
        for (int T = tid; T < TN * FI; T += 256) {
            const int nl = T / FI, o = T % FI;
            const int n = n0 + nl;
            float acc = Pprev[(size_t)n * PWP + 9 * FI + o];   // root + bias
            const int d = min(cnt_t[n], CAP);
            const float* mb = msgin + (size_t)n * CAP * FI + o;
            #pragma unroll 4
            for (int j = 0; j < d; j++) acc += mb[(size_t)j * FI];
            htile[nl * HS + o] = fmaxf(acc, 0.f);
        }
    }

    // ---- phase B: two W halves ----
    const int nl = tid >> 3, lane = tid & 7;
    const int n = n0 + nl;
    const float* hr = &htile[nl * HS];
    float4* Pr4 = (float4*)(Pout + (size_t)n * PW);
    #pragma unroll
    for (int half = 0; half < 2; half++) {
        __syncthreads();   // htile ready (h=0) / prev half's gemm done (h=1)
        for (int t = tid; t < FI * C4H; t += 256) {
            const int f = t / C4H, cq = t % C4H;
            const int cc = half * C4H + cq;
            const int s = cc / O4, oq = cc % O4;
            const float* src;
            if (s < 8)       src = We + (size_t)s * FI * FO2 + f * FO2 + oq * 4;
            else if (s == 8) src = be + f * FO2 + oq * 4;
            else             src = root + f * FO2 + oq * 4;
            ((float4*)Wlds)[t] = *(const float4*)src;
        }
        __syncthreads();
        const float4* W4 = (const float4*)Wlds;
        for (int cq = lane; cq < C4H; cq += 8) {
            const int cc = half * C4H + cq;
            float4 a = {0.f, 0.f, 0.f, 0.f};
            #pragma unroll
            for (int f = 0; f < FI; f++) {
                const float  hf = hr[f];
                const float4 w  = W4[f * C4H + cq];
                a.x = fmaf(hf, w.x, a.x); a.y = fmaf(hf, w.y, a.y);
                a.z = fmaf(hf, w.z, a.z); a.w = fmaf(hf, w.w, a.w);
            }
            if (cc >= 9 * O4) {
                const float4 b4 = ((const float4*)bias)[cc - 9 * O4];
                a.x += b4.x; a.y += b4.y; a.z += b4.z; a.w += b4.w;
            }
            Pr4[cc] = a;
        }
    }
    __syncthreads();   // all Pout rows of the tile written

    // ---- phase C: out-edge messages from block-local P ----
    const int ds = min(cnt_s[n], CAP);
    const float4* Pr = (const float4*)(Pout + (size_t)n * PW);
    for (int j = lane; j < ds; j += 8) {
        const size_t ss = (size_t)n * CAP + j;
        const int st = adj_t[ss];
        if (st < 0) continue;
        const float4* e4 = (const float4*)(e_src + ss * 8);
        const float4 ea = e4[0], eb = e4[1];
        const float es[8] = {ea.x, ea.y, ea.z, ea.w, eb.x, eb.y, eb.z, eb.w};
        float4 acc[O4];
        #pragma unroll
        for (int q = 0; q < O4; q++) acc[q] = Pr[8 * O4 + q];   // bias channel
        #pragma unroll
        for (int s = 0; s < 8; s++) {
            const float w = es[s];
            #pragma unroll
            for (int q = 0; q < O4; q++) {
                const float4 v = Pr[s * O4 + q];
                acc[q].x = fmaf(w, v.x, acc[q].x);
                acc[q].y = fmaf(w, v.y, acc[q].y);
                acc[q].z = fmaf(w, v.z, acc[q].z);
                acc[q].w = fmaf(w, v.w, acc[q].w);
            }
        }
        float4* mo = (float4*)(msgout + (size_t)st * FO2);
        #pragma unroll
        for (int q = 0; q < O4; q++) mo[q] = acc[q];
    }
}

// ===========================================================================
// D6: final gather (msg3 + root3) + relu + column-sum -> g (24 atomics/block)
// ===========================================================================
__global__ __launch_bounds__(256)
void gather_colsum_kernel(const float* __restrict__ P3,    // width 240
                          const float* __restrict__ msg3,  // width 24
                          const int* __restrict__ cnt_t, float* __restrict__ g)
{
    constexpr int FO = 24;
    __shared__ float gl[FO];
    const int tid = threadIdx.x;
    if (tid < FO) gl[tid] = 0.f;
    __syncthreads();

    const int n0 = blockIdx.x * TN;
    for (int T = tid; T < TN * FO; T += 256) {
        const int nl = T / FO, o = T % FO;
        const int n = n0 + nl;
        float acc = P3[(size_t)n * 240 + 9 * FO + o];
        const int d = min(cnt_t[n], CAP);
        const float* mb = msg3 + (size_t)n * CAP * FO + o;
        #pragma unroll 4
        for (int j = 0; j < d; j++) acc += mb[(size_t)j * FO];
        atomicAdd(&gl[o], fmaxf(acc, 0.f));
    }
    __syncthreads();
    if (tid < FO) unsafeAtomicAdd(&g[tid], gl[tid]);
}

// ===========================================================================
// D7: MLP head, 16 blocks, outputs partitioned, barrier between layers.
// ===========================================================================
__global__ __launch_bounds__(256)
void mlp_kernel(const float* __restrict__ g, int* __restrict__ ctr,
                const float* __restrict__ Wd1, const float* __restrict__ bd1,
                const float* __restrict__ Wd2, const float* __restrict__ bd2,
                const float* __restrict__ Wd3, const float* __restrict__ bd3,
                const float* __restrict__ Wd4, const float* __restrict__ bd4,
                const float* __restrict__ Wd5, const float* __restrict__ bd5,
                const float* __restrict__ Wd6, const float* __restrict__ bd6,
                float* __restrict__ m1, float* __restrict__ m2,
                float* __restrict__ m3, float* __restrict__ m4,
                float* __restrict__ m5, float* __restrict__ out)
{
    __shared__ float xs[768];
    __shared__ float red[256];
    const int tid = threadIdx.x, b = blockIdx.x;

    // L1: 24 -> 96 (6 outputs/block)
    if (tid < 24) xs[tid] = g[tid];
    __syncthreads();
    if (tid < 6) {
        const int o = b * 6 + tid;
        float a = bd1[o];
        #pragma unroll
        for (int i = 0; i < 24; i++) a = fmaf(xs[i], Wd1[i * 96 + o], a);
        gstore(&m1[o], fmaxf(a, 0.f));
    }
    mbarrier(ctr, 1 * NBM, true);

    // L2: 96 -> 256 (16 outputs/block; 16 kg x K=6)
    if (tid < 96) xs[tid] = gload(&m1[tid]);
    __syncthreads();
    {
        const int o = (tid & 15), kg = tid >> 4;
        float a = 0.f;
        #pragma unroll
        for (int i = kg * 6; i < kg * 6 + 6; i++)
            a = fmaf(xs[i], Wd2[i * 256 + b * 16 + o], a);
        red[tid] = a;
    }
    __syncthreads();
    if (tid < 16) {
        float s = bd2[b * 16 + tid];
        #pragma unroll
        for (int k = 0; k < 16; k++) s += red[k * 16 + tid];
        gstore(&m2[b * 16 + tid], fmaxf(s, 0.f));
    }
    mbarrier(ctr, 2 * NBM, true);

    // L3: 256 -> 768 (48 outputs/block; 4 kg x K=64)
    for (int i = tid; i < 256; i += 256) xs[i] = gload(&m2[i]);
    __syncthreads();
    if (tid < 192) {
        const int o = b * 48 + (tid % 48), kg = tid / 48;
        float a = 0.f;
        #pragma unroll 8
        for (int i = kg * 64; i < kg * 64 + 64; i++)
            a = fmaf(xs[i], Wd3[(size_t)i * 768 + o], a);
        red[tid] = a;
    }
    __syncthreads();
    if (tid < 48) {
        float s = bd3[b * 48 + tid] + red[tid] + red[48 + tid] + red[96 + tid] + red[144 + tid];
        gstore(&m3[b * 48 + tid], fmaxf(s, 0.f));
    }
    mbarrier(ctr, 3 * NBM, true);

    // L4: 768 -> 512 (32 outputs/block; 8 kg x K=96)
    for (int i = tid; i < 768; i += 256) xs[i] = gload(&m3[i]);
    __syncthreads();
    {
        const int o = b * 32 + (tid & 31), kg = tid >> 5;
        float a = 0.f;
        #pragma unroll 8
        for (int i = kg * 96; i < kg * 96 + 96; i++)
            a = fmaf(xs[i], Wd4[(size_t)i * 512 + o], a);
        red[tid] = a;
    }
    __syncthreads();
    if (tid < 32) {
        float s = bd4[b * 32 + tid];
        #pragma unroll
        for (int k = 0; k < 8; k++) s += red[k * 32 + tid];
        gstore(&m4[b * 32 + tid], fmaxf(s, 0.f));
    }
    mbarrier(ctr, 4 * NBM, true);

    // L5: 512 -> 64 (4 outputs/block; 64 kg x K=8)
    for (int i = tid; i < 512; i += 256) xs[i] = gload(&m4[i]);
    __syncthreads();
    {
        const int o = (tid & 3), kg = tid >> 2;
        float a = 0.f;
        #pragma unroll
        for (int i = kg * 8; i < kg * 8 + 8; i++)
            a = fmaf(xs[i], Wd5[(size_t)i * 64 + b * 4 + o], a);
        red[tid] = a;
    }
    __syncthreads();
    if (tid < 4) {
        float s = bd5[b * 4 + tid];
        #pragma unroll
        for (int k = 0; k < 64; k++) s += red[k * 4 + tid];
        gstore(&m5[b * 4 + tid], fmaxf(s, 0.f));
    }
    mbarrier(ctr, 5 * NBM, b == 0);

    // L6: 64 -> 1
    if (b == 0 && tid < 64) {
        float v = gload(&m5[tid]) * Wd6[tid];
        #pragma unroll
        for (int off = 32; off > 0; off >>= 1)
            v += __shfl_down(v, off, 64);
        if (tid == 0) out[0] = v + bd6[0];
    }
}

// ===========================================================================
extern "C" void kernel_launch(void* const* d_in, const int* in_sizes, int n_in,
                              void* d_out, int out_size, void* d_ws, size_t ws_size,
                              hipStream_t stream)
{
    const float* x     = (const float*)d_in[0];
    const int*   eidx  = (const int*)  d_in[1];
    const float* e     = (const float*)d_in[2];
    const float* We1   = (const float*)d_in[3];  const float* be1 = (const float*)d_in[4];
    const float* root1 = (const float*)d_in[5];  const float* b1  = (const float*)d_in[6];
    const float* We2   = (const float*)d_in[7];  const float* be2 = (const float*)d_in[8];
    const float* root2 = (const float*)d_in[9];  const float* b2  = (const float*)d_in[10];
    const float* We3   = (const float*)d_in[11]; const float* be3 = (const float*)d_in[12];
    const float* root3 = (const float*)d_in[13]; const float* b3  = (const float*)d_in[14];
    const float* Wd1 = (const float*)d_in[15]; const float* bd1 = (const float*)d_in[16];
    const float* Wd2 = (const float*)d_in[17]; const float* bd2 = (const float*)d_in[18];
    const float* Wd3 = (const float*)d_in[19]; const float* bd3 = (const float*)d_in[20];
    const float* Wd4 = (const float*)d_in[21]; const float* bd4 = (const float*)d_in[22];
    const float* Wd5 = (const float*)d_in[23]; const float* bd5 = (const float*)d_in[24];
    const float* Wd6 = (const float*)d_in[25]; const float* bd6 = (const float*)d_in[26];

    // ---- workspace layout (4-byte units) ----
    int*   wi    = (int*)d_ws;
    int*   cnt_t = wi;                        //        0 ..    20000
    int*   cnt_s = wi + 20000;                //    20000 ..    40000
    float* g     = (float*)d_ws + 40000;      //    40000 ..    40024
    int*   mctr  = wi + 40032;                //    40032 (own line)
    float* m1    = (float*)d_ws + 40064;      //    96
    float* m2    = m1 + 96;                   //    256
    float* m3    = m2 + 256;                  //    768
    float* m4    = m3 + 768;                  //    512
    float* m5    = m4 + 512;                  //    64   (ends 41760)
    int*   adj_t = wi + 41760;                //    640,000 (NN*CAP)
    float* wf    = (float*)d_ws;
    float* e_src = wf + 681760;               //  5,120,000 (NN*CAP*8)
    float* msgA  = wf + 5801760;              // 25,600,000 (NN*CAP*40) — L1 & L3 msgs
    float* msgB  = wf + 31401760;             // 15,360,000 (NN*CAP*24) — L2 msgs
    float* Pa    = wf + 46761760;             //  8,000,000 (NN*400)    — P1
    float* Pb    = wf + 54761760;             //  4,800,000 (NN*240)    — P2
    float* Pc    = wf + 59561760;             //  4,800,000 (NN*240)    — P3
    // total 64,361,760 floats ~= 257.4 MB (ws is 268 MB)

    // D1: zero cnt_t, cnt_s, g, mctr (+ m vectors, harmless)
    hipMemsetAsync(d_ws, 0, (size_t)41760 * sizeof(int), stream);

    // D2: src-major edge buckets
    fill_kernel<<<625, 256, 0, stream>>>(eidx, e, cnt_t, cnt_s, adj_t, e_src);

    // D3: layer 1 (x -> P1 + msg1)
    layer_kernel<16, 40, true><<<625, 256, 0, stream>>>(
        x, nullptr, nullptr, cnt_t, cnt_s, adj_t, e_src,
        We1, be1, root1, b1, Pa, msgA);

    // D4: layer 2 (gather msg1 + P1-root -> h1 -> P2 + msg2)
    layer_kernel<40, 24, false><<<625, 256, 0, stream>>>(
        nullptr, Pa, msgA, cnt_t, cnt_s, adj_t, e_src,
        We2, be2, root2, b2, Pb, msgB);

    // D5: layer 3 (gather msg2 + P2-root -> h2 -> P3 + msg3)
    layer_kernel<24, 24, false><<<625, 256, 0, stream>>>(
        nullptr, Pb, msgB, cnt_t, cnt_s, adj_t, e_src,
        We3, be3, root3, b3, Pc, msgA);   // msg3 reuses msgA region

    // D6: final gather + column sum -> g
    gather_colsum_kernel<<<625, 256, 0, stream>>>(Pc, msgA, cnt_t, g);

    // D7: MLP head
    mlp_kernel<<<NBM, 256, 0, stream>>>(g, mctr,
                                        Wd1, bd1, Wd2, bd2, Wd3, bd3,
                                        Wd4, bd4, Wd5, bd5, Wd6, bd6,
                                        m1, m2, m3, m4, m5, (float*)d_out);
}